// Round 20
// baseline (420.389 us; speedup 1.0000x reference)
//
#include <hip/hip_runtime.h>
#include <hip/hip_bf16.h>
#include <stdint.h>

// TernaryLinear: out = scale * (x_bf16 @ wq_bf16^T), scale = mean|W|+1e-8
// M=8192, K=2048, N=8192. fp32 in/out.
//
// GEMM: R17/R19 skeleton, but B operand comes DIRECT FROM GLOBAL into regs
// (A stays LDS-staged). Removes B's LDS reads (64KB) + writes (32KB) per
// tile per CU = -37.5% LDS traffic. Serial-sum model (calibrated R14:
// T ~= T_LDS + T_MFMA) predicts ~-20% kernel time.
// Per-tile schedule (CB = current A buffer, T = K-tile):
//   ph1: GLB_B23(T)   | rd a03 (8, LDS) | MFMA Q00 [a03 x b01(T), b01 loaded prev ph3]
//   ph2: rd a47 (8)                     | MFMA Q40 | BAR (CB.A dead: a03/a47 retired)
//   ph3: GLB_B01(T+1) | STAGE A(T+2)h0->CB | MFMA Q02 [a03 x b23(T), 2-phase slack]
//   ph4: STAGE A(T+2)h1                 | MFMA Q42 | vm(12) BAR
// vmcnt ledger (in-order retire, m135): at ph4 wait, issue order is
// [A(T+1)h0,h1 (prev ph3/4)] [B23(T):4] [B01(T+1):4] [A(T+2)h0:2] [A(T+2)h1:2]
// -> exactly 12 younger than A(T+1)h1 -> vm(12) forces A(T+1) (next tile's
// reads). B-reg consumers get compiler-emitted counted vmcnt automatically.
// Reg liveness: b01 last use Q40@ph2, reloaded ph3; b23 last use Q42@ph4,
// reloaded next ph1. WAR (A only): CB.A readers retire before ph2-end BAR =>
// ph3/ph4 stages safe. setprio fences kept (R18: load-bearing vs raw BAR).
// Prologue: A(0)->C0, B01(0), A(1)->C1; vm(8) retires A(0) (leaves B01+A(1)).
// Tail: tile30 vm(8) [A(31):4 older than B23(30):4+B01(31):4]; tile31 no
// B01(32) load (would read OOB), auto-waits only.
// 4x8 supertiled XCD map (R11: FETCH 549->200MB). LDS = 2x32KB A buffers.

typedef __attribute__((ext_vector_type(8))) short   s16x8;
typedef __attribute__((ext_vector_type(4))) float   f32x4;

#define K_DIM   2048
#define K2      4096        // row stride bytes (bf16)
#define N_DIM   8192
#define N4      4194304     // 8192*2048/4

// ---------------- scale reduction ----------------
__global__ void k_abs_part(const float4* __restrict__ w4, float* __restrict__ part) {
    int tid = blockIdx.x * 256 + threadIdx.x;
    float s = 0.f;
    for (int i = tid; i < N4; i += gridDim.x * 256) {
        float4 v = w4[i];
        s += fabsf(v.x) + fabsf(v.y) + fabsf(v.z) + fabsf(v.w);
    }
    for (int off = 32; off > 0; off >>= 1) s += __shfl_down(s, off, 64);
    __shared__ float tmp[4];
    int lane = threadIdx.x & 63, wid = threadIdx.x >> 6;
    if (lane == 0) tmp[wid] = s;
    __syncthreads();
    if (threadIdx.x == 0) part[blockIdx.x] = tmp[0] + tmp[1] + tmp[2] + tmp[3];
}

__global__ void k_abs_final(const float* __restrict__ part, float* __restrict__ scale) {
    float s = part[threadIdx.x] + part[threadIdx.x + 256] +
              part[threadIdx.x + 512] + part[threadIdx.x + 768];
    for (int off = 32; off > 0; off >>= 1) s += __shfl_down(s, off, 64);
    __shared__ float tmp[4];
    int lane = threadIdx.x & 63, wid = threadIdx.x >> 6;
    if (lane == 0) tmp[wid] = s;
    __syncthreads();
    if (threadIdx.x == 0) scale[0] = (tmp[0] + tmp[1] + tmp[2] + tmp[3]) / 16777216.0f + 1e-8f;
}

// ---------------- fused W-quant + X-convert ----------------
__device__ __forceinline__ uint32_t f2b(float f) {
    uint32_t u = __builtin_bit_cast(uint32_t, f);
    return (u + 0x7FFFu + ((u >> 16) & 1u)) >> 16;  // RNE
}

__global__ void k_prep(const float4* __restrict__ w4, const float4* __restrict__ x4,
                       const float* __restrict__ scale_p,
                       uint2* __restrict__ wq, uint2* __restrict__ xb) {
    int tid = (blockIdx.x & 2047) * 256 + threadIdx.x;
    if (blockIdx.x < 2048) {
        const float sc = *scale_p;
        for (int i = tid; i < N4; i += 2048 * 256) {
            float4 v = w4[i];
            float q0 = rintf(v.x / sc), q1 = rintf(v.y / sc);
            float q2 = rintf(v.z / sc), q3 = rintf(v.w / sc);
            uint32_t b0 = (q0 == 0.f) ? 0u : (q0 > 0.f ? 0x3F80u : 0xBF80u);
            uint32_t b1 = (q1 == 0.f) ? 0u : (q1 > 0.f ? 0x3F80u : 0xBF80u);
            uint32_t b2 = (q2 == 0.f) ? 0u : (q2 > 0.f ? 0x3F80u : 0xBF80u);
            uint32_t b3 = (q3 == 0.f) ? 0u : (q3 > 0.f ? 0x3F80u : 0xBF80u);
            uint2 o; o.x = b0 | (b1 << 16); o.y = b2 | (b3 << 16);
            wq[i] = o;
        }
    } else {
        for (int i = tid; i < N4; i += 2048 * 256) {
            float4 v = x4[i];
            uint2 o;
            o.x = f2b(v.x) | (f2b(v.y) << 16);
            o.y = f2b(v.z) | (f2b(v.w) << 16);
            xb[i] = o;
        }
    }
}

// ---------------- GEMM ----------------
__device__ __forceinline__ void mfma16(f32x4& c, s16x8 a, s16x8 b) {
    asm("v_mfma_f32_16x16x32_bf16 %0, %1, %2, %0" : "+v"(c) : "v"(a), "v"(b));
}
__device__ __forceinline__ void load_lds16(const void* g, void* l) {
    __builtin_amdgcn_global_load_lds(
        (const __attribute__((address_space(1))) uint32_t*)g,
        (__attribute__((address_space(3))) uint32_t*)l, 16, 0, 0);
}

#define SBAR __builtin_amdgcn_s_barrier()
#define WAIT_VM(N) asm volatile("s_waitcnt vmcnt(" #N ")" ::: "memory")

// LDS byte map (64 KiB): buf0.A = 0, buf1.A = 32768 (A only; B is in regs)
#define C0 0
#define C1 32768

__global__ __launch_bounds__(512, 2) void k_gemm(
    const unsigned short* __restrict__ Xb,
    const unsigned short* __restrict__ Wb,
    const float* __restrict__ scale_p,
    float* __restrict__ out)
{
    extern __shared__ uint8_t smem[];
    const int tid  = threadIdx.x;
    const int lane = tid & 63;
    const int wid  = tid >> 6;
    const int wr   = wid >> 2;          // 0..1
    const int wc   = wid & 3;           // 0..3

    // 4x8 supertiled XCD mapping (bijective; proven R11: FETCH 549->200MB)
    const int bid = blockIdx.x;
    const int xcd = bid & 7;
    const int l   = bid >> 3;
    const int tileRow = xcd * 4 + ((l >> 3) & 3);   // 0..31
    const int tileCol = (l >> 5) * 8 + (l & 7);     // 0..31

    const uint8_t* gA = (const uint8_t*)Xb + (size_t)tileRow * 256 * K2;

    // A staging (unchanged): thread t covers rows srow, srow+64 of a 128-row
    // half; physical LDS slot c of row r holds global col-slot (c ^ (r&7)).
    const int srow = tid >> 3, sslot = tid & 7;
    const size_t srcOff = (size_t)srow * K2 + (size_t)((sslot ^ (srow & 7)) * 16);
    const uint8_t* gAs = gA + srcOff;
    const int dstOff = tid * 16;

    // A LDS read bases; frag m adds m*2048 (16 rows * 128B)
    const int rA = wr * 128 + (lane & 15);
    const int h  = lane >> 4;           // 0..3
    const int pA0 = rA * 128 + (((h    ) ^ (rA & 7)) * 16);
    const int pA1 = rA * 128 + (((4 + h) ^ (rA & 7)) * 16);

    // B direct-global per-lane base: row = tileCol*256 + wc*64 + (lane&15),
    // byte = row*K2 + h*16. Frag (n,kk) adds n*16 rows (65536B) + kt*128 + kk*64.
    // Identical element mapping to the old LDS path (verified layout).
    const uint8_t* gBl = (const uint8_t*)Wb +
        ((size_t)tileCol * 256 + (size_t)(wc * 64 + (lane & 15))) * K2 + (size_t)(h * 16);

    s16x8 a[8][2], b[4][2];
    f32x4 acc[8][4];
    #pragma unroll
    for (int m = 0; m < 8; ++m)
        #pragma unroll
        for (int n = 0; n < 4; ++n) acc[m][n] = (f32x4){0.f, 0.f, 0.f, 0.f};

#define LD8(OFF) (*(const s16x8*)(smem + (OFF)))
#define STAGE(LBASE, GP, BOFF) do { \
    load_lds16((GP) + (BOFF),          smem + (LBASE) + dstOff); \
    load_lds16((GP) + (BOFF) + 262144, smem + (LBASE) + 8192 + dstOff); } while (0)

#define RD_A03(AB) do { _Pragma("unroll") for (int m = 0; m < 4; ++m) { \
    a[m][0] = LD8((AB) + pA0 + m * 2048); a[m][1] = LD8((AB) + pA1 + m * 2048); } } while (0)
#define RD_A47(AB) do { _Pragma("unroll") for (int m = 4; m < 8; ++m) { \
    a[m][0] = LD8((AB) + pA0 + m * 2048); a[m][1] = LD8((AB) + pA1 + m * 2048); } } while (0)

#define GLB_B01(KT) do { _Pragma("unroll") for (int n = 0; n < 2; ++n) \
    _Pragma("unroll") for (int kk = 0; kk < 2; ++kk) \
        b[n][kk] = *(const s16x8*)(gBl + (size_t)n * 65536 + (size_t)(KT) * 128 + kk * 64); } while (0)
#define GLB_B23(KT) do { _Pragma("unroll") for (int n = 2; n < 4; ++n) \
    _Pragma("unroll") for (int kk = 0; kk < 2; ++kk) \
        b[n][kk] = *(const s16x8*)(gBl + (size_t)n * 65536 + (size_t)(KT) * 128 + kk * 64); } while (0)

// setprio bracket REQUIRED (R18): pins MFMA clusters (and feeding reads)
// against the raw barriers.
#define MFMA_Q(MLO, NLO) do { \
    __builtin_amdgcn_s_setprio(1); \
    _Pragma("unroll") for (int kk = 0; kk < 2; ++kk) \
        _Pragma("unroll") for (int m = 0; m < 4; ++m) \
            _Pragma("unroll") for (int n = 0; n < 2; ++n) \
                mfma16(acc[(MLO) + m][(NLO) + n], a[(MLO) + m][kk], b[(NLO) + n][kk]); \
    __builtin_amdgcn_s_setprio(0); } while (0)

    // prologue: A(0)->C0; B01(0); A(1)->C1. vm(8) retires A(0) (12 in flight
    // -> 8: leaves B01(0)+A(1)); BAR makes A(0) visible chip-wide.
    STAGE(C0,        gAs, 0);   STAGE(C0 + 16384, gAs, 524288);
    GLB_B01(0);
    STAGE(C1,        gAs, 128); STAGE(C1 + 16384, gAs, 524288 + 128);
    WAIT_VM(8);
    SBAR;

    #pragma unroll 1
    for (int i = 0; i < 15; ++i) {
        const int t0 = 2 * i, t1 = 2 * i + 1;
        // ---- even tile t0 on C0 ----
        GLB_B23(t0);
        RD_A03(C0);
        MFMA_Q(0, 0);
        RD_A47(C0);
        MFMA_Q(4, 0);
        SBAR;                                   // C0.A dead
        GLB_B01(t0 + 1);
        STAGE(C0, gAs, (t0 + 2) * 128);
        MFMA_Q(0, 2);
        STAGE(C0 + 16384, gAs, 524288 + (t0 + 2) * 128);
        MFMA_Q(4, 2);
        WAIT_VM(12); SBAR;                      // A(t0+1) landed
        // ---- odd tile t1 on C1 ----
        GLB_B23(t1);
        RD_A03(C1);
        MFMA_Q(0, 0);
        RD_A47(C1);
        MFMA_Q(4, 0);
        SBAR;                                   // C1.A dead
        GLB_B01(t1 + 1);
        STAGE(C1, gAs, (t1 + 2) * 128);
        MFMA_Q(0, 2);
        STAGE(C1 + 16384, gAs, 524288 + (t1 + 2) * 128);
        MFMA_Q(4, 2);
        WAIT_VM(12); SBAR;                      // A(t1+1) landed
    }

    // tail: tile 30 (C0; no stages; vm(8) forces A(31)), tile 31 (C1; no
    // B01(32) load - would be OOB; compiler auto-waits cover b23(31)).
    {
        GLB_B23(30);
        RD_A03(C0);
        MFMA_Q(0, 0);
        RD_A47(C0);
        MFMA_Q(4, 0);
        SBAR;
        GLB_B01(31);
        MFMA_Q(0, 2);
        MFMA_Q(4, 2);
        WAIT_VM(8); SBAR;                       // A(31) landed
        GLB_B23(31);
        RD_A03(C1);
        MFMA_Q(0, 0);
        RD_A47(C1);
        MFMA_Q(4, 0);
        MFMA_Q(0, 2);
        MFMA_Q(4, 2);
    }

    // epilogue: C[row][col], col=lane&15, row=(lane>>4)*4+j (verified mapping)
    const float sc = *scale_p;
    const int orow0 = tileRow * 256 + wr * 128 + ((lane >> 4) << 2);
    const int ocol0 = tileCol * 256 + wc * 64 + (lane & 15);
    #pragma unroll
    for (int m = 0; m < 8; ++m)
        #pragma unroll
        for (int n = 0; n < 4; ++n)
            #pragma unroll
            for (int j = 0; j < 4; ++j)
                out[(size_t)(orow0 + m * 16 + j) * N_DIM + (ocol0 + n * 16)] = acc[m][n][j] * sc;

#undef LD8
#undef STAGE
#undef RD_A03
#undef RD_A47
#undef GLB_B01
#undef GLB_B23
#undef MFMA_Q
}

// ---------------- launch ----------------
extern "C" void kernel_launch(void* const* d_in, const int* in_sizes, int n_in,
                              void* d_out, int out_size, void* d_ws, size_t ws_size,
                              hipStream_t stream) {
    const float* x = (const float*)d_in[0];
    const float* w = (const float*)d_in[1];
    float* out = (float*)d_out;
    uint8_t* ws = (uint8_t*)d_ws;

    float* part  = (float*)ws;                       // 1024 floats
    float* scale = (float*)(ws + 4096);              // 1 float
    unsigned short* Xb = (unsigned short*)(ws + 8192);
    unsigned short* Wb = (unsigned short*)(ws + 8192 + 33554432ull);

    (void)hipFuncSetAttribute((const void*)k_gemm,
                              hipFuncAttributeMaxDynamicSharedMemorySize, 65536);

    hipLaunchKernelGGL(k_abs_part, dim3(1024), dim3(256), 0, stream, (const float4*)w, part);
    hipLaunchKernelGGL(k_abs_final, dim3(1), dim3(256), 0, stream, part, scale);
    hipLaunchKernelGGL(k_prep, dim3(4096), dim3(256), 0, stream,
                       (const float4*)w, (const float4*)x, scale, (uint2*)Wb, (uint2*)Xb);
    hipLaunchKernelGGL(k_gemm, dim3(1024), dim3(512), 65536, stream, Xb, Wb, scale, out);
}

// Round 21
// 277.248 us; speedup vs baseline: 1.5163x; 1.5163x over previous
//
#include <hip/hip_runtime.h>
#include <hip/hip_bf16.h>
#include <stdint.h>

// TernaryLinear: out = scale * (x_bf16 @ wq_bf16^T), scale = mean|W|+1e-8
// M=8192, K=2048, N=8192. fp32 in/out.
//
// FINAL: R17/R19 configuration (best passing: ~245us gemm / ~277us total).
// Session record: 394 -> 277us via (1) bf16 MFMA pipeline w/ counted-vmcnt
// minimal-barrier schedule, (2) 4x8 supertiled XCD mapping (FETCH 549->200MB),
// (3) SCHED0 removal (null but harmless), setprio KEPT (R18: load-bearing
// scheduling fence -- without a side-effecting bracket the compiler sinks
// MFMA clusters + feeding ds_reads across raw barriers -> cross-wave WAR race).
// Rejected by measurement: 8-phase barrier-per-phase ports (3x regressions),
// 2-blocks/CU 128-tile, 32x32x16 (both swizzles), NT stores, B-direct-global
// (uncoalesced: lanes 4KB apart -> 16 cache lines/instr).
// Schedule (hardware-validated WAR/RAW ledger):
//   ph1: STAGE B(T+1)h0 | rd a03,b01 (12) | MFMA Q00
//   ph2: STAGE B(T+1)h1 | rd a47 (8)      | MFMA Q40 | BAR (buf.A dead)
//   ph3: STAGE A(T+2)h0 | rd b23 (4)      | MFMA Q02
//   ph4: STAGE A(T+2)h1 |                 | MFMA Q42 | vm(4) BAR (T+1 landed)

typedef __attribute__((ext_vector_type(8))) short   s16x8;
typedef __attribute__((ext_vector_type(4))) float   f32x4;

#define K_DIM   2048
#define K2      4096        // row stride bytes (bf16)
#define N_DIM   8192
#define N4      4194304     // 8192*2048/4

// ---------------- scale reduction ----------------
__global__ void k_abs_part(const float4* __restrict__ w4, float* __restrict__ part) {
    int tid = blockIdx.x * 256 + threadIdx.x;
    float s = 0.f;
    for (int i = tid; i < N4; i += gridDim.x * 256) {
        float4 v = w4[i];
        s += fabsf(v.x) + fabsf(v.y) + fabsf(v.z) + fabsf(v.w);
    }
    for (int off = 32; off > 0; off >>= 1) s += __shfl_down(s, off, 64);
    __shared__ float tmp[4];
    int lane = threadIdx.x & 63, wid = threadIdx.x >> 6;
    if (lane == 0) tmp[wid] = s;
    __syncthreads();
    if (threadIdx.x == 0) part[blockIdx.x] = tmp[0] + tmp[1] + tmp[2] + tmp[3];
}

__global__ void k_abs_final(const float* __restrict__ part, float* __restrict__ scale) {
    float s = part[threadIdx.x] + part[threadIdx.x + 256] +
              part[threadIdx.x + 512] + part[threadIdx.x + 768];
    for (int off = 32; off > 0; off >>= 1) s += __shfl_down(s, off, 64);
    __shared__ float tmp[4];
    int lane = threadIdx.x & 63, wid = threadIdx.x >> 6;
    if (lane == 0) tmp[wid] = s;
    __syncthreads();
    if (threadIdx.x == 0) scale[0] = (tmp[0] + tmp[1] + tmp[2] + tmp[3]) / 16777216.0f + 1e-8f;
}

// ---------------- fused W-quant + X-convert ----------------
__device__ __forceinline__ uint32_t f2b(float f) {
    uint32_t u = __builtin_bit_cast(uint32_t, f);
    return (u + 0x7FFFu + ((u >> 16) & 1u)) >> 16;  // RNE
}

__global__ void k_prep(const float4* __restrict__ w4, const float4* __restrict__ x4,
                       const float* __restrict__ scale_p,
                       uint2* __restrict__ wq, uint2* __restrict__ xb) {
    int tid = (blockIdx.x & 2047) * 256 + threadIdx.x;
    if (blockIdx.x < 2048) {
        const float sc = *scale_p;
        for (int i = tid; i < N4; i += 2048 * 256) {
            float4 v = w4[i];
            float q0 = rintf(v.x / sc), q1 = rintf(v.y / sc);
            float q2 = rintf(v.z / sc), q3 = rintf(v.w / sc);
            uint32_t b0 = (q0 == 0.f) ? 0u : (q0 > 0.f ? 0x3F80u : 0xBF80u);
            uint32_t b1 = (q1 == 0.f) ? 0u : (q1 > 0.f ? 0x3F80u : 0xBF80u);
            uint32_t b2 = (q2 == 0.f) ? 0u : (q2 > 0.f ? 0x3F80u : 0xBF80u);
            uint32_t b3 = (q3 == 0.f) ? 0u : (q3 > 0.f ? 0x3F80u : 0xBF80u);
            uint2 o; o.x = b0 | (b1 << 16); o.y = b2 | (b3 << 16);
            wq[i] = o;
        }
    } else {
        for (int i = tid; i < N4; i += 2048 * 256) {
            float4 v = x4[i];
            uint2 o;
            o.x = f2b(v.x) | (f2b(v.y) << 16);
            o.y = f2b(v.z) | (f2b(v.w) << 16);
            xb[i] = o;
        }
    }
}

// ---------------- GEMM ----------------
__device__ __forceinline__ void mfma16(f32x4& c, s16x8 a, s16x8 b) {
    asm("v_mfma_f32_16x16x32_bf16 %0, %1, %2, %0" : "+v"(c) : "v"(a), "v"(b));
}
__device__ __forceinline__ void load_lds16(const void* g, void* l) {
    __builtin_amdgcn_global_load_lds(
        (const __attribute__((address_space(1))) uint32_t*)g,
        (__attribute__((address_space(3))) uint32_t*)l, 16, 0, 0);
}

#define SBAR __builtin_amdgcn_s_barrier()
#define WAIT_VM(N) asm volatile("s_waitcnt vmcnt(" #N ")" ::: "memory")

// LDS byte map (128 KiB): buf0.A=0, buf0.B=32768, buf1.A=65536, buf1.B=98304
#define C0 0
#define C1 65536

__global__ __launch_bounds__(512, 2) void k_gemm(
    const unsigned short* __restrict__ Xb,
    const unsigned short* __restrict__ Wb,
    const float* __restrict__ scale_p,
    float* __restrict__ out)
{
    extern __shared__ uint8_t smem[];
    const int tid  = threadIdx.x;
    const int lane = tid & 63;
    const int wid  = tid >> 6;
    const int wr   = wid >> 2;          // 0..1
    const int wc   = wid & 3;           // 0..3

    // 4x8 supertiled XCD mapping (bijective; proven R11: FETCH 549->200MB)
    const int bid = blockIdx.x;
    const int xcd = bid & 7;
    const int l   = bid >> 3;
    const int tileRow = xcd * 4 + ((l >> 3) & 3);   // 0..31
    const int tileCol = (l >> 5) * 8 + (l & 7);     // 0..31

    const uint8_t* gA = (const uint8_t*)Xb + (size_t)tileRow * 256 * K2;
    const uint8_t* gB = (const uint8_t*)Wb + (size_t)tileCol * 256 * K2;

    // staging: thread t covers row srow and srow+64 of a 128-row x 64-K half-region.
    // physical LDS slot c of row r holds global col-slot (c ^ (r&7))  (XOR swizzle).
    const int srow = tid >> 3, sslot = tid & 7;
    const size_t srcOff = (size_t)srow * K2 + (size_t)((sslot ^ (srow & 7)) * 16);
    const uint8_t* gAs = gA + srcOff;
    const uint8_t* gBs = gB + srcOff;
    const int dstOff = tid * 16;

    // LDS read bases (byte offsets); frag m adds m*2048 (16 rows * 128B)
    const int rA = wr * 128 + (lane & 15);
    const int rB = wc * 64  + (lane & 15);
    const int h  = lane >> 4;
    const int pA0 = rA * 128 + (((h    ) ^ (rA & 7)) * 16);
    const int pA1 = rA * 128 + (((4 + h) ^ (rA & 7)) * 16);
    const int pB0 = rB * 128 + (((h    ) ^ (rB & 7)) * 16);
    const int pB1 = rB * 128 + (((4 + h) ^ (rB & 7)) * 16);

    s16x8 a[8][2], b[4][2];
    f32x4 acc[8][4];
    #pragma unroll
    for (int m = 0; m < 8; ++m)
        #pragma unroll
        for (int n = 0; n < 4; ++n) acc[m][n] = (f32x4){0.f, 0.f, 0.f, 0.f};

#define LD8(OFF) (*(const s16x8*)(smem + (OFF)))
#define STAGE(LBASE, GP, BOFF) do { \
    load_lds16((GP) + (BOFF),          smem + (LBASE) + dstOff); \
    load_lds16((GP) + (BOFF) + 262144, smem + (LBASE) + 8192 + dstOff); } while (0)

#define RD_A03(AB) do { _Pragma("unroll") for (int m = 0; m < 4; ++m) { \
    a[m][0] = LD8((AB) + pA0 + m * 2048); a[m][1] = LD8((AB) + pA1 + m * 2048); } } while (0)
#define RD_A47(AB) do { _Pragma("unroll") for (int m = 4; m < 8; ++m) { \
    a[m][0] = LD8((AB) + pA0 + m * 2048); a[m][1] = LD8((AB) + pA1 + m * 2048); } } while (0)
#define RD_B01(AB) do { _Pragma("unroll") for (int n = 0; n < 2; ++n) { \
    b[n][0] = LD8((AB) + 32768 + pB0 + n * 2048); b[n][1] = LD8((AB) + 32768 + pB1 + n * 2048); } } while (0)
#define RD_B23(AB) do { _Pragma("unroll") for (int n = 2; n < 4; ++n) { \
    b[n][0] = LD8((AB) + 32768 + pB0 + n * 2048); b[n][1] = LD8((AB) + 32768 + pB1 + n * 2048); } } while (0)

// setprio bracket REQUIRED (R18): side-effecting ops pin the MFMA cluster
// (and transitively its feeding ds_reads) against the raw barriers.
#define MFMA_Q(MLO, NLO) do { \
    __builtin_amdgcn_s_setprio(1); \
    _Pragma("unroll") for (int kk = 0; kk < 2; ++kk) \
        _Pragma("unroll") for (int m = 0; m < 4; ++m) \
            _Pragma("unroll") for (int n = 0; n < 2; ++n) \
                mfma16(acc[(MLO) + m][(NLO) + n], a[(MLO) + m][kk], b[(NLO) + n][kk]); \
    __builtin_amdgcn_s_setprio(0); } while (0)

    // prologue: stage tiles 0 (C0) and 1 (C1) fully; force tile 0, leave tile
    // 1's 8 loads in flight.
    STAGE(C0,         gAs, 0);   STAGE(C0 + 16384, gAs, 524288);
    STAGE(C0 + 32768, gBs, 0);   STAGE(C0 + 49152, gBs, 524288);
    STAGE(C1,         gAs, 128); STAGE(C1 + 16384, gAs, 524288 + 128);
    STAGE(C1 + 32768, gBs, 128); STAGE(C1 + 49152, gBs, 524288 + 128);
    WAIT_VM(8);
    SBAR;

    #pragma unroll 1
    for (int i = 0; i < 15; ++i) {
        const int kb1 = (2 * i + 1) * 128;   // T+1
        const int kb2 = kb1 + 128;           // T+2
        const int kb3 = kb1 + 256;           // T+3
        // ---- even tile T on C0 ----
        // ph1
        STAGE(C1 + 32768, gBs, kb1);
        RD_A03(C0); RD_B01(C0);
        MFMA_Q(0, 0);
        // ph2
        STAGE(C1 + 49152, gBs, 524288 + kb1);
        RD_A47(C0);
        MFMA_Q(4, 0);
        SBAR;                                   // buf0.A dead
        // ph3
        STAGE(C0, gAs, kb2);
        RD_B23(C0);
        MFMA_Q(0, 2);
        // ph4
        STAGE(C0 + 16384, gAs, 524288 + kb2);
        MFMA_Q(4, 2);
        WAIT_VM(4); SBAR;                       // T+1 landed; buf0.B dead
        // ---- odd tile T+1 on C1 ----
        // ph5
        STAGE(C0 + 32768, gBs, kb2);
        RD_A03(C1); RD_B01(C1);
        MFMA_Q(0, 0);
        // ph6
        STAGE(C0 + 49152, gBs, 524288 + kb2);
        RD_A47(C1);
        MFMA_Q(4, 0);
        SBAR;                                   // buf1.A dead
        // ph7
        STAGE(C1, gAs, kb3);
        RD_B23(C1);
        MFMA_Q(0, 2);
        // ph8
        STAGE(C1 + 16384, gAs, 524288 + kb3);
        MFMA_Q(4, 2);
        WAIT_VM(4); SBAR;                       // T+2 landed; buf1.B dead
    }

    // peeled i=15: tiles 30 (C0), 31 (C1); stage only B_31; then drain
    {
        const int kb1 = 31 * 128;
        STAGE(C1 + 32768, gBs, kb1);
        RD_A03(C0); RD_B01(C0);
        MFMA_Q(0, 0);
        STAGE(C1 + 49152, gBs, 524288 + kb1);
        RD_A47(C0);
        MFMA_Q(4, 0);
        SBAR;
        RD_B23(C0);
        MFMA_Q(0, 2);
        MFMA_Q(4, 2);
        WAIT_VM(0); SBAR;                       // all of tile 31 landed
        RD_A03(C1); RD_B01(C1);
        MFMA_Q(0, 0);
        RD_A47(C1);
        MFMA_Q(4, 0);
        RD_B23(C1);
        MFMA_Q(0, 2);
        MFMA_Q(4, 2);
    }

    // epilogue: C[row][col], col=lane&15, row=(lane>>4)*4+j (verified mapping)
    const float sc = *scale_p;
    const int orow0 = tileRow * 256 + wr * 128 + ((lane >> 4) << 2);
    const int ocol0 = tileCol * 256 + wc * 64 + (lane & 15);
    #pragma unroll
    for (int m = 0; m < 8; ++m)
        #pragma unroll
        for (int n = 0; n < 4; ++n)
            #pragma unroll
            for (int j = 0; j < 4; ++j)
                out[(size_t)(orow0 + m * 16 + j) * N_DIM + (ocol0 + n * 16)] = acc[m][n][j] * sc;

#undef LD8
#undef STAGE
#undef RD_A03
#undef RD_A47
#undef RD_B01
#undef RD_B23
#undef MFMA_Q
}

// ---------------- launch ----------------
extern "C" void kernel_launch(void* const* d_in, const int* in_sizes, int n_in,
                              void* d_out, int out_size, void* d_ws, size_t ws_size,
                              hipStream_t stream) {
    const float* x = (const float*)d_in[0];
    const float* w = (const float*)d_in[1];
    float* out = (float*)d_out;
    uint8_t* ws = (uint8_t*)d_ws;

    float* part  = (float*)ws;                       // 1024 floats
    float* scale = (float*)(ws + 4096);              // 1 float
    unsigned short* Xb = (unsigned short*)(ws + 8192);
    unsigned short* Wb = (unsigned short*)(ws + 8192 + 33554432ull);

    (void)hipFuncSetAttribute((const void*)k_gemm,
                              hipFuncAttributeMaxDynamicSharedMemorySize, 131072);

    hipLaunchKernelGGL(k_abs_part, dim3(1024), dim3(256), 0, stream, (const float4*)w, part);
    hipLaunchKernelGGL(k_abs_final, dim3(1), dim3(256), 0, stream, part, scale);
    hipLaunchKernelGGL(k_prep, dim3(4096), dim3(256), 0, stream,
                       (const float4*)w, (const float4*)x, scale, (uint2*)Wb, (uint2*)Xb);
    hipLaunchKernelGGL(k_gemm, dim3(1024), dim3(512), 131072, stream, Xb, Wb, scale, out);
}